// Round 1
// baseline (39660.855 us; speedup 1.0000x reference)
//
#include <hip/hip_runtime.h>
#include <math.h>

#define B_ 64
#define T_ 12
#define N_ 800
#define CIN_ 2
#define H_ 64
#define HOR_ 12
#define TCI_ 60
#define TCH_ 2
#define KAPPA_ 0.05f
#define IN0_ 4
#define ROWS_ 51200  // B_*N_

__device__ __forceinline__ float sigm(float x) { return 1.0f / (1.0f + expf(-x)); }

// ---------------- small kernels ----------------

__global__ void transp_kernel(const float* __restrict__ G, float* __restrict__ A1) {
  int idx = blockIdx.x * 256 + threadIdx.x;
  if (idx >= N_ * N_) return;
  int m = idx / N_, n = idx - m * N_;
  A1[idx] = G[n * N_ + m];
}

// C = 2*A@A - I   (800x800, A row-major)
__global__ __launch_bounds__(256) void gemm_t2(const float* __restrict__ A, float* __restrict__ C) {
  int tid = threadIdx.x;
  int tx = tid & 15, ty = tid >> 4;
  int rowBase = blockIdx.y * 64, colBase = blockIdx.x * 64;
  __shared__ float As[16][68];
  __shared__ float Bs[16][68];
  float acc[4][4] = {};
  for (int k0 = 0; k0 < N_; k0 += 16) {
    __syncthreads();
#pragma unroll
    for (int e = tid; e < 1024; e += 256) {
      int r = e >> 4, c = e & 15;
      int gr = rowBase + r;
      As[c][r] = (gr < N_) ? A[gr * N_ + k0 + c] : 0.f;
    }
#pragma unroll
    for (int e = tid; e < 1024; e += 256) {
      int r = e >> 6, c = e & 63;
      int gc = colBase + c;
      Bs[r][c] = (gc < N_) ? A[(k0 + r) * N_ + gc] : 0.f;
    }
    __syncthreads();
#pragma unroll
    for (int kk = 0; kk < 16; ++kk) {
      float4 a4 = *(const float4*)&As[kk][ty * 4];
      float4 b4 = *(const float4*)&Bs[kk][tx * 4];
      float av[4] = {a4.x, a4.y, a4.z, a4.w};
      float bv[4] = {b4.x, b4.y, b4.z, b4.w};
#pragma unroll
      for (int i = 0; i < 4; ++i)
#pragma unroll
        for (int j = 0; j < 4; ++j) acc[i][j] += av[i] * bv[j];
    }
  }
#pragma unroll
  for (int i = 0; i < 4; ++i) {
    int m = rowBase + ty * 4 + i;
    if (m >= N_) continue;
#pragma unroll
    for (int j = 0; j < 4; ++j) {
      int n = colBase + tx * 4 + j;
      if (n < N_) C[m * N_ + n] = 2.f * acc[i][j] - (m == n ? 1.f : 0.f);
    }
  }
}

// batched: for b in [0,64), k in {1,2}:  Zout[b][m][k*P+inOff+c] = sum_n A_k[m][n]*Z[b][n][inOff+c]
__global__ __launch_bounds__(256) void graph_gemm(float* __restrict__ Z, int ldz, int inOff, int inW, int P,
                                                  const float* __restrict__ A1, const float* __restrict__ A2) {
  int tid = threadIdx.x;
  int tx = tid & 15, ty = tid >> 4;
  int b = blockIdx.z >> 1;
  int kblk = (blockIdx.z & 1) + 1;
  const float* __restrict__ A = (kblk == 1) ? A1 : A2;
  float* Zb = Z + (size_t)b * N_ * ldz;
  const float* Zin = Zb + inOff;
  float* Zout = Zb + kblk * P + inOff;
  int rowBase = blockIdx.y * 64, colBase = blockIdx.x * 64;
  __shared__ float As[16][68];
  __shared__ float Bs[16][68];
  float acc[4][4] = {};
  for (int k0 = 0; k0 < N_; k0 += 16) {
    __syncthreads();
#pragma unroll
    for (int e = tid; e < 1024; e += 256) {
      int r = e >> 4, c = e & 15;
      int gr = rowBase + r;
      As[c][r] = (gr < N_) ? A[gr * N_ + k0 + c] : 0.f;
    }
#pragma unroll
    for (int e = tid; e < 1024; e += 256) {
      int r = e >> 6, c = e & 63;
      int gc = colBase + c;
      Bs[r][c] = (gc < inW) ? Zin[(size_t)(k0 + r) * ldz + gc] : 0.f;
    }
    __syncthreads();
#pragma unroll
    for (int kk = 0; kk < 16; ++kk) {
      float4 a4 = *(const float4*)&As[kk][ty * 4];
      float4 b4 = *(const float4*)&Bs[kk][tx * 4];
      float av[4] = {a4.x, a4.y, a4.z, a4.w};
      float bv[4] = {b4.x, b4.y, b4.z, b4.w};
#pragma unroll
      for (int i = 0; i < 4; ++i)
#pragma unroll
        for (int j = 0; j < 4; ++j) acc[i][j] += av[i] * bv[j];
    }
  }
#pragma unroll
  for (int i = 0; i < 4; ++i) {
    int m = rowBase + ty * 4 + i;
    if (m >= N_) continue;
#pragma unroll
    for (int j = 0; j < 4; ++j) {
      int c = colBase + tx * 4 + j;
      if (c < inW) Zout[(size_t)m * ldz + c] = acc[i][j];
    }
  }
}

// projection GEMM: (51200 x K3) @ (K3 x NC) with fused GRU epilogue.
// MODE 0 (gate, NC=128): u=sigmoid(first 64)->U ; r=sigmoid(last 64); Zw[row][Pin+j]=r*h
// MODE 1 (cand, NC=64):  c=tanh(v); h = (1-u)*h + u*c
template <int TNn, int MODE>
__global__ __launch_bounds__(256) void proj_gemm(const float* __restrict__ Z, int ldz, int K3, int Pin,
                                                 const float* __restrict__ W, const float* __restrict__ bias,
                                                 float* __restrict__ U, float* __restrict__ h,
                                                 float* __restrict__ Zw) {
  const int NC = TNn * 16;
  int tid = threadIdx.x;
  int tx = tid & 15, ty = tid >> 4;
  int rowBase = blockIdx.y * 64;
  __shared__ float As[16][68];
  __shared__ float Bs[16][NC + 4];
  float acc[4][TNn];
#pragma unroll
  for (int i = 0; i < 4; ++i)
#pragma unroll
    for (int j = 0; j < TNn; ++j) acc[i][j] = 0.f;

  for (int k0 = 0; k0 < K3; k0 += 16) {
    __syncthreads();
#pragma unroll
    for (int e = tid; e < 1024; e += 256) {
      int r = e >> 4, c = e & 15;
      As[c][r] = (k0 + c < K3) ? Z[(size_t)(rowBase + r) * ldz + k0 + c] : 0.f;
    }
#pragma unroll
    for (int e = tid; e < 16 * NC; e += 256) {
      int r = e / NC, c = e - r * NC;
      Bs[r][c] = (k0 + r < K3) ? W[(size_t)(k0 + r) * NC + c] : 0.f;
    }
    __syncthreads();
#pragma unroll
    for (int kk = 0; kk < 16; ++kk) {
      float4 a4 = *(const float4*)&As[kk][ty * 4];
      float av[4] = {a4.x, a4.y, a4.z, a4.w};
      float bv[TNn];
#pragma unroll
      for (int j4 = 0; j4 < TNn / 4; ++j4) {
        float4 b4 = *(const float4*)&Bs[kk][tx * TNn + j4 * 4];
        bv[j4 * 4 + 0] = b4.x; bv[j4 * 4 + 1] = b4.y; bv[j4 * 4 + 2] = b4.z; bv[j4 * 4 + 3] = b4.w;
      }
#pragma unroll
      for (int i = 0; i < 4; ++i)
#pragma unroll
        for (int j = 0; j < TNn; ++j) acc[i][j] += av[i] * bv[j];
    }
  }
#pragma unroll
  for (int i = 0; i < 4; ++i) {
    int row = rowBase + ty * 4 + i;
#pragma unroll
    for (int j = 0; j < TNn; ++j) {
      int col = tx * TNn + j;
      float v = acc[i][j] + bias[col];
      if (MODE == 0) {
        if (col < H_) {
          U[(size_t)row * H_ + col] = sigm(v);
        } else {
          int jj = col - H_;
          Zw[(size_t)row * ldz + Pin + jj] = sigm(v) * h[(size_t)row * H_ + jj];
        }
      } else {
        float cc = tanhf(v);
        float u = U[(size_t)row * H_ + col];
        float hv = h[(size_t)row * H_ + col];
        h[(size_t)row * H_ + col] = (1.f - u) * hv + u * cc;
      }
    }
  }
}

__global__ void pack_enc0(float* __restrict__ Z, const float* __restrict__ xseq,
                          const float* __restrict__ emb, const float* __restrict__ h0, int t) {
  int idx = blockIdx.x * 256 + threadIdx.x;
  if (idx >= ROWS_ * 68) return;
  int row = idx / 68, c = idx - row * 68;
  int b = row / N_, n = row - b * N_;
  float v;
  if (c < CIN_) v = xseq[((size_t)(b * T_ + t) * N_ + n) * CIN_ + c];
  else if (c < IN0_) v = emb[(size_t)(b * T_ + t) * (N_ * TCH_) + n * TCH_ + (c - CIN_)];
  else v = h0[(size_t)row * H_ + (c - IN0_)];
  Z[(size_t)row * 204 + c] = v;
}

__global__ void pack_dec0(float* __restrict__ Z, const float* __restrict__ dout,
                          const float* __restrict__ emb, const float* __restrict__ h0, int t) {
  int idx = blockIdx.x * 256 + threadIdx.x;
  if (idx >= ROWS_ * 68) return;
  int row = idx / 68, c = idx - row * 68;
  int b = row / N_, n = row - b * N_;
  float v;
  if (c < CIN_) v = (t == 0) ? 0.f : dout[((size_t)(b * HOR_ + (t - 1)) * N_ + n) * CIN_ + c];
  else if (c < IN0_) v = emb[(size_t)(b * HOR_ + t) * (N_ * TCH_) + n * TCH_ + (c - CIN_)];
  else v = h0[(size_t)row * H_ + (c - IN0_)];
  Z[(size_t)row * 204 + c] = v;
}

__global__ void pack_l1(float* __restrict__ Z, const float* __restrict__ h0, const float* __restrict__ h1) {
  int idx = blockIdx.x * 256 + threadIdx.x;
  if (idx >= ROWS_ * 128) return;
  int row = idx >> 7, c = idx & 127;
  Z[(size_t)row * 384 + c] = (c < 64) ? h0[(size_t)row * 64 + c] : h1[(size_t)row * 64 + (c - 64)];
}

// Wcat[0:P]=W0+k(W1+W2); Wcat[P:2P]=(1-k)W1; Wcat[2P:3P]=(1-k)W2
__global__ void wcat_kernel(const float* __restrict__ W, float* __restrict__ Wo, int P, int O) {
  int idx = blockIdx.x * 256 + threadIdx.x;
  if (idx >= P * O) return;
  int i = idx / O, o = idx - i * O;
  float w0 = W[(size_t)i * O + o];
  float w1 = W[(size_t)(P + i) * O + o];
  float w2 = W[(size_t)(2 * P + i) * O + o];
  Wo[(size_t)i * O + o] = w0 + KAPPA_ * (w1 + w2);
  Wo[(size_t)(P + i) * O + o] = (1.f - KAPPA_) * w1;
  Wo[(size_t)(2 * P + i) * O + o] = (1.f - KAPPA_) * w2;
}

__global__ void mlp_hid(const float* __restrict__ tin, const float* __restrict__ W1,
                        const float* __restrict__ b1, float* __restrict__ hid, int Rtot) {
  int idx = blockIdx.x * 256 + threadIdx.x;
  if (idx >= Rtot * 10) return;
  int r = idx / 10, j = idx - r * 10;
  float a = b1[j];
  for (int k = 0; k < TCI_; ++k) a += tin[(size_t)r * TCI_ + k] * W1[k * 10 + j];
  hid[idx] = a;
}

__global__ void mlp_out(const float* __restrict__ hid, const float* __restrict__ W2,
                        const float* __restrict__ b2, float* __restrict__ emb, int Rtot) {
  int idx = blockIdx.x * 256 + threadIdx.x;
  if (idx >= Rtot * 1600) return;
  int r = idx / 1600, o = idx - r * 1600;
  float a = b2[o];
#pragma unroll
  for (int k = 0; k < 10; ++k) a += hid[r * 10 + k] * W2[k * 1600 + o];
  emb[idx] = a;
}

// per b: q = h1row(51200) @ Wa(51200x8); att=softmax(q@memT); attvec=att@mem
__global__ __launch_bounds__(256) void memq_kernel(const float* __restrict__ h1, const float* __restrict__ Wa,
                                                   const float* __restrict__ mem, float* __restrict__ attvec) {
  int b = blockIdx.x;
  __shared__ float red[256][8];
  float acc[8] = {};
  const float* hrow = h1 + (size_t)b * 51200;
  for (int i = threadIdx.x; i < 51200; i += 256) {
    float hv = hrow[i];
#pragma unroll
    for (int j = 0; j < 8; ++j) acc[j] += hv * Wa[(size_t)i * 8 + j];
  }
#pragma unroll
  for (int j = 0; j < 8; ++j) red[threadIdx.x][j] = acc[j];
  __syncthreads();
  for (int s = 128; s > 0; s >>= 1) {
    if (threadIdx.x < s) {
#pragma unroll
      for (int j = 0; j < 8; ++j) red[threadIdx.x][j] += red[threadIdx.x + s][j];
    }
    __syncthreads();
  }
  if (threadIdx.x == 0) {
    float q[8];
#pragma unroll
    for (int j = 0; j < 8; ++j) q[j] = red[0][j];
    float sco[4], mx = -1e30f;
#pragma unroll
    for (int m = 0; m < 4; ++m) {
      float s = 0.f;
#pragma unroll
      for (int d = 0; d < 8; ++d) s += q[d] * mem[m * 8 + d];
      sco[m] = s;
      mx = fmaxf(mx, s);
    }
    float se = 0.f;
#pragma unroll
    for (int m = 0; m < 4; ++m) { sco[m] = expf(sco[m] - mx); se += sco[m]; }
#pragma unroll
    for (int d = 0; d < 8; ++d) {
      float av = 0.f;
#pragma unroll
      for (int m = 0; m < 4; ++m) av += (sco[m] / se) * mem[m * 8 + d];
      attvec[b * 8 + d] = av;
    }
  }
}

__global__ void outproj_kernel(const float* __restrict__ h1, const float* __restrict__ attvec,
                               const float* __restrict__ fc, const float* __restrict__ projW,
                               const float* __restrict__ projb, float* __restrict__ dout, int t) {
  int row = blockIdx.x * 256 + threadIdx.x;
  if (row >= ROWS_) return;
  int b = row / N_, n = row - b * N_;
  const float* av = attvec + b * 8;
  float attm[8];
#pragma unroll
  for (int d = 0; d < 8; ++d) {
    float s = 0.f;
#pragma unroll
    for (int m = 0; m < 8; ++m) s += av[m] * fc[(size_t)m * 6400 + n * 8 + d];
    attm[d] = s;
  }
  float o0 = projb[0], o1 = projb[1];
  for (int j = 0; j < 64; ++j) {
    float hv = h1[(size_t)row * 64 + j];
    o0 += hv * projW[j * 2 + 0];
    o1 += hv * projW[j * 2 + 1];
  }
#pragma unroll
  for (int d = 0; d < 8; ++d) {
    o0 += attm[d] * projW[(64 + d) * 2 + 0];
    o1 += attm[d] * projW[(64 + d) * 2 + 1];
  }
  o0 = fmaxf(o0, 0.f);
  o1 = fmaxf(o1, 0.f);
  size_t base = ((size_t)(b * HOR_ + t) * N_ + n) * 2;
  dout[base + 0] = o0;
  dout[base + 1] = o1;
}

// ---------------- host ----------------

extern "C" void kernel_launch(void* const* d_in, const int* in_sizes, int n_in,
                              void* d_out, int out_size, void* d_ws, size_t ws_size,
                              hipStream_t stream) {
  const float* x_seq = (const float*)d_in[0];
  const float* t_x = (const float*)d_in[1];
  const float* t_y = (const float*)d_in[2];
  const float* G = (const float*)d_in[3];
  const float* enc_Wg0 = (const float*)d_in[4];
  const float* enc_bg0 = (const float*)d_in[5];
  const float* enc_Wc0 = (const float*)d_in[6];
  const float* enc_bc0 = (const float*)d_in[7];
  const float* enc_Wg1 = (const float*)d_in[8];
  const float* enc_bg1 = (const float*)d_in[9];
  const float* enc_Wc1 = (const float*)d_in[10];
  const float* enc_bc1 = (const float*)d_in[11];
  const float* dec_Wg0 = (const float*)d_in[12];
  const float* dec_bg0 = (const float*)d_in[13];
  const float* dec_Wc0 = (const float*)d_in[14];
  const float* dec_bc0 = (const float*)d_in[15];
  const float* dec_Wg1 = (const float*)d_in[16];
  const float* dec_bg1 = (const float*)d_in[17];
  const float* dec_Wc1 = (const float*)d_in[18];
  const float* dec_bc1 = (const float*)d_in[19];
  const float* mlp_W1 = (const float*)d_in[20];
  const float* mlp_b1 = (const float*)d_in[21];
  const float* mlp_W2 = (const float*)d_in[22];
  const float* mlp_b2 = (const float*)d_in[23];
  const float* memoryp = (const float*)d_in[24];
  const float* Wa = (const float*)d_in[25];
  const float* fcp = (const float*)d_in[26];
  const float* projW = (const float*)d_in[27];
  const float* projb = (const float*)d_in[28];
  float* dout = (float*)d_out;

  float* ws = (float*)d_ws;
  size_t off = 0;
  auto alloc = [&](size_t nel) { float* p = ws + off; off += nel; return p; };
  float* A1 = alloc(640000);
  float* A2 = alloc(640000);
  float* Zg = alloc((size_t)ROWS_ * 384);
  float* U = alloc((size_t)ROWS_ * 64);
  float* h0 = alloc((size_t)ROWS_ * 64);
  float* h1 = alloc((size_t)ROWS_ * 64);
  float* txe = alloc((size_t)768 * 1600);
  float* tye = alloc((size_t)768 * 1600);
  float* hidb = alloc(7680);
  float* attv = alloc(512);
  float* wge0 = alloc(204 * 128);
  float* wce0 = alloc(204 * 64);
  float* wge1 = alloc(384 * 128);
  float* wce1 = alloc(384 * 64);
  float* wgd0 = alloc(204 * 128);
  float* wcd0 = alloc(204 * 64);
  float* wgd1 = alloc(384 * 128);
  float* wcd1 = alloc(384 * 64);

  hipMemsetAsync(h0, 0, (size_t)ROWS_ * 64 * sizeof(float), stream);
  hipMemsetAsync(h1, 0, (size_t)ROWS_ * 64 * sizeof(float), stream);

  // precompute graph operators
  transp_kernel<<<2500, 256, 0, stream>>>(G, A1);
  gemm_t2<<<dim3(13, 13), 256, 0, stream>>>(A1, A2);

  // preprocess weights
  wcat_kernel<<<(68 * 128 + 255) / 256, 256, 0, stream>>>(enc_Wg0, wge0, 68, 128);
  wcat_kernel<<<(68 * 64 + 255) / 256, 256, 0, stream>>>(enc_Wc0, wce0, 68, 64);
  wcat_kernel<<<(128 * 128 + 255) / 256, 256, 0, stream>>>(enc_Wg1, wge1, 128, 128);
  wcat_kernel<<<(128 * 64 + 255) / 256, 256, 0, stream>>>(enc_Wc1, wce1, 128, 64);
  wcat_kernel<<<(68 * 128 + 255) / 256, 256, 0, stream>>>(dec_Wg0, wgd0, 68, 128);
  wcat_kernel<<<(68 * 64 + 255) / 256, 256, 0, stream>>>(dec_Wc0, wcd0, 68, 64);
  wcat_kernel<<<(128 * 128 + 255) / 256, 256, 0, stream>>>(dec_Wg1, wgd1, 128, 128);
  wcat_kernel<<<(128 * 64 + 255) / 256, 256, 0, stream>>>(dec_Wc1, wcd1, 128, 64);

  // time covariate embeddings
  mlp_hid<<<30, 256, 0, stream>>>(t_x, mlp_W1, mlp_b1, hidb, 768);
  mlp_out<<<4800, 256, 0, stream>>>(hidb, mlp_W2, mlp_b2, txe, 768);
  mlp_hid<<<30, 256, 0, stream>>>(t_y, mlp_W1, mlp_b1, hidb, 768);
  mlp_out<<<4800, 256, 0, stream>>>(hidb, mlp_W2, mlp_b2, tye, 768);

  auto run_cell = [&](int layer, const float* Wg, const float* bg, const float* Wc, const float* bc, float* h) {
    int Pin = layer ? 64 : 4;
    int P = layer ? 128 : 68;
    int ldz = 3 * P;
    int K3 = 3 * P;
    graph_gemm<<<dim3((P + 63) / 64, 13, 128), 256, 0, stream>>>(Zg, ldz, 0, P, P, A1, A2);
    proj_gemm<8, 0><<<dim3(1, 800), 256, 0, stream>>>(Zg, ldz, K3, Pin, Wg, bg, U, h, Zg);
    graph_gemm<<<dim3(1, 13, 128), 256, 0, stream>>>(Zg, ldz, Pin, 64, P, A1, A2);
    proj_gemm<4, 1><<<dim3(1, 800), 256, 0, stream>>>(Zg, ldz, K3, Pin, Wc, bc, U, h, Zg);
  };

  // encoder
  for (int t = 0; t < T_; ++t) {
    pack_enc0<<<13600, 256, 0, stream>>>(Zg, x_seq, txe, h0, t);
    run_cell(0, wge0, enc_bg0, wce0, enc_bc0, h0);
    pack_l1<<<25600, 256, 0, stream>>>(Zg, h0, h1);
    run_cell(1, wge1, enc_bg1, wce1, enc_bc1, h1);
  }

  // decoder
  for (int t = 0; t < HOR_; ++t) {
    pack_dec0<<<13600, 256, 0, stream>>>(Zg, dout, tye, h0, t);
    run_cell(0, wgd0, dec_bg0, wcd0, dec_bc0, h0);
    pack_l1<<<25600, 256, 0, stream>>>(Zg, h0, h1);
    run_cell(1, wgd1, dec_bg1, wcd1, dec_bc1, h1);
    memq_kernel<<<64, 256, 0, stream>>>(h1, Wa, memoryp, attv);
    outproj_kernel<<<200, 256, 0, stream>>>(h1, attv, fcp, projW, projb, dout, t);
  }
}

// Round 2
// 19134.885 us; speedup vs baseline: 2.0727x; 2.0727x over previous
//
#include <hip/hip_runtime.h>
#include <math.h>

#define B_ 64
#define T_ 12
#define N_ 800
#define CIN_ 2
#define H_ 64
#define HOR_ 12
#define TCI_ 60
#define TCH_ 2
#define KAPPA_ 0.05f
#define IN0_ 4
#define ROWS_ 51200  // B_*N_

typedef _Float16 f16_t;
typedef _Float16 half8 __attribute__((ext_vector_type(8)));
typedef float f32x4 __attribute__((ext_vector_type(4)));

__device__ __forceinline__ float sigm(float x) { return 1.0f / (1.0f + expf(-x)); }

// ---------------- small kernels ----------------

__global__ void transp_kernel(const float* __restrict__ G, float* __restrict__ A1) {
  int idx = blockIdx.x * 256 + threadIdx.x;
  if (idx >= N_ * N_) return;
  int m = idx / N_, n = idx - m * N_;
  A1[idx] = G[n * N_ + m];
}

// C = 2*A@A - I   (800x800, A row-major)
__global__ __launch_bounds__(256) void gemm_t2(const float* __restrict__ A, float* __restrict__ C) {
  int tid = threadIdx.x;
  int tx = tid & 15, ty = tid >> 4;
  int rowBase = blockIdx.y * 64, colBase = blockIdx.x * 64;
  __shared__ float As[16][68];
  __shared__ float Bs[16][68];
  float acc[4][4] = {};
  for (int k0 = 0; k0 < N_; k0 += 16) {
    __syncthreads();
#pragma unroll
    for (int e = tid; e < 1024; e += 256) {
      int r = e >> 4, c = e & 15;
      int gr = rowBase + r;
      As[c][r] = (gr < N_) ? A[gr * N_ + k0 + c] : 0.f;
    }
#pragma unroll
    for (int e = tid; e < 1024; e += 256) {
      int r = e >> 6, c = e & 63;
      int gc = colBase + c;
      Bs[r][c] = (gc < N_) ? A[(k0 + r) * N_ + gc] : 0.f;
    }
    __syncthreads();
#pragma unroll
    for (int kk = 0; kk < 16; ++kk) {
      float4 a4 = *(const float4*)&As[kk][ty * 4];
      float4 b4 = *(const float4*)&Bs[kk][tx * 4];
      float av[4] = {a4.x, a4.y, a4.z, a4.w};
      float bv[4] = {b4.x, b4.y, b4.z, b4.w};
#pragma unroll
      for (int i = 0; i < 4; ++i)
#pragma unroll
        for (int j = 0; j < 4; ++j) acc[i][j] += av[i] * bv[j];
    }
  }
#pragma unroll
  for (int i = 0; i < 4; ++i) {
    int m = rowBase + ty * 4 + i;
    if (m >= N_) continue;
#pragma unroll
    for (int j = 0; j < 4; ++j) {
      int n = colBase + tx * 4 + j;
      if (n < N_) C[m * N_ + n] = 2.f * acc[i][j] - (m == n ? 1.f : 0.f);
    }
  }
}

// split fp32 -> (hi fp16, lo fp16 scaled by 2^11)
__global__ void split_fp16(const float* __restrict__ A, f16_t* __restrict__ Ah, f16_t* __restrict__ Al, int n) {
  int i = blockIdx.x * 256 + threadIdx.x;
  if (i >= n) return;
  float a = A[i];
  f16_t h = (f16_t)a;
  Ah[i] = h;
  Al[i] = (f16_t)((a - (float)h) * 2048.0f);
}

// batched MFMA graph GEMM (fp16x3 split):
// for b in [0,64), k in {1,2}:  Zout[b][m][k*P+inOff+c] = sum_n A_k[m][n]*Z[b][n][inOff+c]
// Block: 128(M) x 64(N), 4 waves (2x2), each wave 64x32. BK=32, mfma 16x16x32_f16.
__global__ __launch_bounds__(256) void graph_mfma(float* __restrict__ Z, int ldz, int inOff, int inW, int P,
                                                  const f16_t* __restrict__ A1h, const f16_t* __restrict__ A1l,
                                                  const f16_t* __restrict__ A2h, const f16_t* __restrict__ A2l) {
  int tid = threadIdx.x;
  int b = blockIdx.z >> 1;
  int kblk = (blockIdx.z & 1) + 1;
  const f16_t* __restrict__ Ah = (kblk == 1) ? A1h : A2h;
  const f16_t* __restrict__ Al = (kblk == 1) ? A1l : A2l;
  float* Zb = Z + (size_t)b * N_ * ldz;
  const float* __restrict__ Zin = Zb + inOff;
  float* __restrict__ Zout = Zb + kblk * P + inOff;
  int rowBase = blockIdx.y * 128;
  int colBase = blockIdx.x * 64;

  // LDS: A planes [128 rows][40 f16 pitch]; Z planes [64 cols][40 f16 pitch] (transposed: row=c, 32 k's)
  __shared__ f16_t AhS[128 * 40];
  __shared__ f16_t AlS[128 * 40];
  __shared__ f16_t ZhS[64 * 40];
  __shared__ f16_t ZlS[64 * 40];

  int lane = tid & 63;
  int wid = tid >> 6;
  int waveM = wid >> 1, waveN = wid & 1;
  int lrow = lane & 15, lgrp = lane >> 4;

  // staging roles
  int arow = tid >> 1, ahalf = tid & 1;          // A: 128 rows x 2 halves of 16 f16
  bool avalid = (rowBase + arow) < N_;
  int zc = tid & 63, zgrp = tid >> 6;            // Z: 64 cols x 4 groups of 8 k's
  bool zvalid = (colBase + zc) < inW;

  f32x4 accM[4][2], accC[4][2];
#pragma unroll
  for (int mt = 0; mt < 4; ++mt)
#pragma unroll
    for (int nt = 0; nt < 2; ++nt) {
      accM[mt][nt] = (f32x4){0.f, 0.f, 0.f, 0.f};
      accC[mt][nt] = (f32x4){0.f, 0.f, 0.f, 0.f};
    }

  for (int k0 = 0; k0 < N_; k0 += 32) {
    __syncthreads();
    // ---- stage A hi/lo (already fp16 in global) ----
    {
      size_t gofs = (size_t)(rowBase + arow) * N_ + k0 + ahalf * 16;
      uint4 zz = {0u, 0u, 0u, 0u};
      uint4 h0 = avalid ? *(const uint4*)(Ah + gofs) : zz;
      uint4 h1 = avalid ? *(const uint4*)(Ah + gofs + 8) : zz;
      uint4 l0 = avalid ? *(const uint4*)(Al + gofs) : zz;
      uint4 l1 = avalid ? *(const uint4*)(Al + gofs + 8) : zz;
      int s = arow * 40 + ahalf * 16;
      *(uint4*)(AhS + s) = h0;
      *(uint4*)(AhS + s + 8) = h1;
      *(uint4*)(AlS + s) = l0;
      *(uint4*)(AlS + s + 8) = l1;
    }
    // ---- stage Z: load fp32 rows, split, write transposed [c][k] ----
    {
      const float* src = Zin + (size_t)(k0 + zgrp * 8) * ldz + colBase + zc;
      half8 vh, vl;
#pragma unroll
      for (int i = 0; i < 8; ++i) {
        float zv = zvalid ? src[(size_t)i * ldz] : 0.f;
        f16_t h = (f16_t)zv;
        vh[i] = h;
        vl[i] = (f16_t)((zv - (float)h) * 2048.0f);
      }
      int s = zc * 40 + zgrp * 8;
      *(half8*)(ZhS + s) = vh;
      *(half8*)(ZlS + s) = vl;
    }
    __syncthreads();
    // ---- fragments + MFMA ----
    half8 fah[4], fal[4];
#pragma unroll
    for (int mt = 0; mt < 4; ++mt) {
      int r = waveM * 64 + mt * 16 + lrow;
      int s = r * 40 + lgrp * 8;
      fah[mt] = *(const half8*)(AhS + s);
      fal[mt] = *(const half8*)(AlS + s);
    }
    half8 fzh[2], fzl[2];
#pragma unroll
    for (int nt = 0; nt < 2; ++nt) {
      int c = waveN * 32 + nt * 16 + lrow;
      int s = c * 40 + lgrp * 8;
      fzh[nt] = *(const half8*)(ZhS + s);
      fzl[nt] = *(const half8*)(ZlS + s);
    }
#pragma unroll
    for (int mt = 0; mt < 4; ++mt)
#pragma unroll
      for (int nt = 0; nt < 2; ++nt) {
        accM[mt][nt] = __builtin_amdgcn_mfma_f32_16x16x32_f16(fah[mt], fzh[nt], accM[mt][nt], 0, 0, 0);
        accC[mt][nt] = __builtin_amdgcn_mfma_f32_16x16x32_f16(fah[mt], fzl[nt], accC[mt][nt], 0, 0, 0);
        accC[mt][nt] = __builtin_amdgcn_mfma_f32_16x16x32_f16(fal[mt], fzh[nt], accC[mt][nt], 0, 0, 0);
      }
  }

  // ---- epilogue: C = accM + accC/2048 ----
#pragma unroll
  for (int mt = 0; mt < 4; ++mt)
#pragma unroll
    for (int nt = 0; nt < 2; ++nt) {
      f32x4 v = accM[mt][nt] + accC[mt][nt] * (1.0f / 2048.0f);
      int c = colBase + waveN * 32 + nt * 16 + lrow;
      if (c < inW) {
#pragma unroll
        for (int j = 0; j < 4; ++j) {
          int r = rowBase + waveM * 64 + mt * 16 + lgrp * 4 + j;
          if (r < N_) Zout[(size_t)r * ldz + c] = v[j];
        }
      }
    }
}

// projection GEMM: (51200 x K3) @ (K3 x NC) with fused GRU epilogue.
// MODE 0 (gate, NC=128): u=sigmoid(first 64)->U ; r=sigmoid(last 64); Zw[row][Pin+j]=r*h
// MODE 1 (cand, NC=64):  c=tanh(v); h = (1-u)*h + u*c
template <int TNn, int MODE>
__global__ __launch_bounds__(256) void proj_gemm(const float* __restrict__ Z, int ldz, int K3, int Pin,
                                                 const float* __restrict__ W, const float* __restrict__ bias,
                                                 float* __restrict__ U, float* __restrict__ h,
                                                 float* __restrict__ Zw) {
  const int NC = TNn * 16;
  int tid = threadIdx.x;
  int tx = tid & 15, ty = tid >> 4;
  int rowBase = blockIdx.y * 64;
  __shared__ float As[16][68];
  __shared__ float Bs[16][NC + 4];
  float acc[4][TNn];
#pragma unroll
  for (int i = 0; i < 4; ++i)
#pragma unroll
    for (int j = 0; j < TNn; ++j) acc[i][j] = 0.f;

  for (int k0 = 0; k0 < K3; k0 += 16) {
    __syncthreads();
#pragma unroll
    for (int e = tid; e < 1024; e += 256) {
      int r = e >> 4, c = e & 15;
      As[c][r] = (k0 + c < K3) ? Z[(size_t)(rowBase + r) * ldz + k0 + c] : 0.f;
    }
#pragma unroll
    for (int e = tid; e < 16 * NC; e += 256) {
      int r = e / NC, c = e - r * NC;
      Bs[r][c] = (k0 + r < K3) ? W[(size_t)(k0 + r) * NC + c] : 0.f;
    }
    __syncthreads();
#pragma unroll
    for (int kk = 0; kk < 16; ++kk) {
      float4 a4 = *(const float4*)&As[kk][ty * 4];
      float av[4] = {a4.x, a4.y, a4.z, a4.w};
      float bv[TNn];
#pragma unroll
      for (int j4 = 0; j4 < TNn / 4; ++j4) {
        float4 b4 = *(const float4*)&Bs[kk][tx * TNn + j4 * 4];
        bv[j4 * 4 + 0] = b4.x; bv[j4 * 4 + 1] = b4.y; bv[j4 * 4 + 2] = b4.z; bv[j4 * 4 + 3] = b4.w;
      }
#pragma unroll
      for (int i = 0; i < 4; ++i)
#pragma unroll
        for (int j = 0; j < TNn; ++j) acc[i][j] += av[i] * bv[j];
    }
  }
#pragma unroll
  for (int i = 0; i < 4; ++i) {
    int row = rowBase + ty * 4 + i;
#pragma unroll
    for (int j = 0; j < TNn; ++j) {
      int col = tx * TNn + j;
      float v = acc[i][j] + bias[col];
      if (MODE == 0) {
        if (col < H_) {
          U[(size_t)row * H_ + col] = sigm(v);
        } else {
          int jj = col - H_;
          Zw[(size_t)row * ldz + Pin + jj] = sigm(v) * h[(size_t)row * H_ + jj];
        }
      } else {
        float cc = tanhf(v);
        float u = U[(size_t)row * H_ + col];
        float hv = h[(size_t)row * H_ + col];
        h[(size_t)row * H_ + col] = (1.f - u) * hv + u * cc;
      }
    }
  }
}

__global__ void pack_enc0(float* __restrict__ Z, const float* __restrict__ xseq,
                          const float* __restrict__ emb, const float* __restrict__ h0, int t) {
  int idx = blockIdx.x * 256 + threadIdx.x;
  if (idx >= ROWS_ * 68) return;
  int row = idx / 68, c = idx - row * 68;
  int b = row / N_, n = row - b * N_;
  float v;
  if (c < CIN_) v = xseq[((size_t)(b * T_ + t) * N_ + n) * CIN_ + c];
  else if (c < IN0_) v = emb[(size_t)(b * T_ + t) * (N_ * TCH_) + n * TCH_ + (c - CIN_)];
  else v = h0[(size_t)row * H_ + (c - IN0_)];
  Z[(size_t)row * 204 + c] = v;
}

__global__ void pack_dec0(float* __restrict__ Z, const float* __restrict__ dout,
                          const float* __restrict__ emb, const float* __restrict__ h0, int t) {
  int idx = blockIdx.x * 256 + threadIdx.x;
  if (idx >= ROWS_ * 68) return;
  int row = idx / 68, c = idx - row * 68;
  int b = row / N_, n = row - b * N_;
  float v;
  if (c < CIN_) v = (t == 0) ? 0.f : dout[((size_t)(b * HOR_ + (t - 1)) * N_ + n) * CIN_ + c];
  else if (c < IN0_) v = emb[(size_t)(b * HOR_ + t) * (N_ * TCH_) + n * TCH_ + (c - CIN_)];
  else v = h0[(size_t)row * H_ + (c - IN0_)];
  Z[(size_t)row * 204 + c] = v;
}

__global__ void pack_l1(float* __restrict__ Z, const float* __restrict__ h0, const float* __restrict__ h1) {
  int idx = blockIdx.x * 256 + threadIdx.x;
  if (idx >= ROWS_ * 128) return;
  int row = idx >> 7, c = idx & 127;
  Z[(size_t)row * 384 + c] = (c < 64) ? h0[(size_t)row * 64 + c] : h1[(size_t)row * 64 + (c - 64)];
}

// Wcat[0:P]=W0+k(W1+W2); Wcat[P:2P]=(1-k)W1; Wcat[2P:3P]=(1-k)W2
__global__ void wcat_kernel(const float* __restrict__ W, float* __restrict__ Wo, int P, int O) {
  int idx = blockIdx.x * 256 + threadIdx.x;
  if (idx >= P * O) return;
  int i = idx / O, o = idx - i * O;
  float w0 = W[(size_t)i * O + o];
  float w1 = W[(size_t)(P + i) * O + o];
  float w2 = W[(size_t)(2 * P + i) * O + o];
  Wo[(size_t)i * O + o] = w0 + KAPPA_ * (w1 + w2);
  Wo[(size_t)(P + i) * O + o] = (1.f - KAPPA_) * w1;
  Wo[(size_t)(2 * P + i) * O + o] = (1.f - KAPPA_) * w2;
}

__global__ void mlp_hid(const float* __restrict__ tin, const float* __restrict__ W1,
                        const float* __restrict__ b1, float* __restrict__ hid, int Rtot) {
  int idx = blockIdx.x * 256 + threadIdx.x;
  if (idx >= Rtot * 10) return;
  int r = idx / 10, j = idx - r * 10;
  float a = b1[j];
  for (int k = 0; k < TCI_; ++k) a += tin[(size_t)r * TCI_ + k] * W1[k * 10 + j];
  hid[idx] = a;
}

__global__ void mlp_out(const float* __restrict__ hid, const float* __restrict__ W2,
                        const float* __restrict__ b2, float* __restrict__ emb, int Rtot) {
  int idx = blockIdx.x * 256 + threadIdx.x;
  if (idx >= Rtot * 1600) return;
  int r = idx / 1600, o = idx - r * 1600;
  float a = b2[o];
#pragma unroll
  for (int k = 0; k < 10; ++k) a += hid[r * 10 + k] * W2[k * 1600 + o];
  emb[idx] = a;
}

// per b: q = h1row(51200) @ Wa(51200x8); att=softmax(q@memT); attvec=att@mem
__global__ __launch_bounds__(256) void memq_kernel(const float* __restrict__ h1, const float* __restrict__ Wa,
                                                   const float* __restrict__ mem, float* __restrict__ attvec) {
  int b = blockIdx.x;
  __shared__ float red[256][8];
  float acc[8] = {};
  const float* hrow = h1 + (size_t)b * 51200;
  for (int i = threadIdx.x; i < 51200; i += 256) {
    float hv = hrow[i];
#pragma unroll
    for (int j = 0; j < 8; ++j) acc[j] += hv * Wa[(size_t)i * 8 + j];
  }
#pragma unroll
  for (int j = 0; j < 8; ++j) red[threadIdx.x][j] = acc[j];
  __syncthreads();
  for (int s = 128; s > 0; s >>= 1) {
    if (threadIdx.x < s) {
#pragma unroll
      for (int j = 0; j < 8; ++j) red[threadIdx.x][j] += red[threadIdx.x + s][j];
    }
    __syncthreads();
  }
  if (threadIdx.x == 0) {
    float q[8];
#pragma unroll
    for (int j = 0; j < 8; ++j) q[j] = red[0][j];
    float sco[4], mx = -1e30f;
#pragma unroll
    for (int m = 0; m < 4; ++m) {
      float s = 0.f;
#pragma unroll
      for (int d = 0; d < 8; ++d) s += q[d] * mem[m * 8 + d];
      sco[m] = s;
      mx = fmaxf(mx, s);
    }
    float se = 0.f;
#pragma unroll
    for (int m = 0; m < 4; ++m) { sco[m] = expf(sco[m] - mx); se += sco[m]; }
#pragma unroll
    for (int d = 0; d < 8; ++d) {
      float av = 0.f;
#pragma unroll
      for (int m = 0; m < 4; ++m) av += (sco[m] / se) * mem[m * 8 + d];
      attvec[b * 8 + d] = av;
    }
  }
}

__global__ void outproj_kernel(const float* __restrict__ h1, const float* __restrict__ attvec,
                               const float* __restrict__ fc, const float* __restrict__ projW,
                               const float* __restrict__ projb, float* __restrict__ dout, int t) {
  int row = blockIdx.x * 256 + threadIdx.x;
  if (row >= ROWS_) return;
  int b = row / N_, n = row - b * N_;
  const float* av = attvec + b * 8;
  float attm[8];
#pragma unroll
  for (int d = 0; d < 8; ++d) {
    float s = 0.f;
#pragma unroll
    for (int m = 0; m < 8; ++m) s += av[m] * fc[(size_t)m * 6400 + n * 8 + d];
    attm[d] = s;
  }
  float o0 = projb[0], o1 = projb[1];
  for (int j = 0; j < 64; ++j) {
    float hv = h1[(size_t)row * 64 + j];
    o0 += hv * projW[j * 2 + 0];
    o1 += hv * projW[j * 2 + 1];
  }
#pragma unroll
  for (int d = 0; d < 8; ++d) {
    o0 += attm[d] * projW[(64 + d) * 2 + 0];
    o1 += attm[d] * projW[(64 + d) * 2 + 1];
  }
  o0 = fmaxf(o0, 0.f);
  o1 = fmaxf(o1, 0.f);
  size_t base = ((size_t)(b * HOR_ + t) * N_ + n) * 2;
  dout[base + 0] = o0;
  dout[base + 1] = o1;
}

// ---------------- host ----------------

extern "C" void kernel_launch(void* const* d_in, const int* in_sizes, int n_in,
                              void* d_out, int out_size, void* d_ws, size_t ws_size,
                              hipStream_t stream) {
  const float* x_seq = (const float*)d_in[0];
  const float* t_x = (const float*)d_in[1];
  const float* t_y = (const float*)d_in[2];
  const float* G = (const float*)d_in[3];
  const float* enc_Wg0 = (const float*)d_in[4];
  const float* enc_bg0 = (const float*)d_in[5];
  const float* enc_Wc0 = (const float*)d_in[6];
  const float* enc_bc0 = (const float*)d_in[7];
  const float* enc_Wg1 = (const float*)d_in[8];
  const float* enc_bg1 = (const float*)d_in[9];
  const float* enc_Wc1 = (const float*)d_in[10];
  const float* enc_bc1 = (const float*)d_in[11];
  const float* dec_Wg0 = (const float*)d_in[12];
  const float* dec_bg0 = (const float*)d_in[13];
  const float* dec_Wc0 = (const float*)d_in[14];
  const float* dec_bc0 = (const float*)d_in[15];
  const float* dec_Wg1 = (const float*)d_in[16];
  const float* dec_bg1 = (const float*)d_in[17];
  const float* dec_Wc1 = (const float*)d_in[18];
  const float* dec_bc1 = (const float*)d_in[19];
  const float* mlp_W1 = (const float*)d_in[20];
  const float* mlp_b1 = (const float*)d_in[21];
  const float* mlp_W2 = (const float*)d_in[22];
  const float* mlp_b2 = (const float*)d_in[23];
  const float* memoryp = (const float*)d_in[24];
  const float* Wa = (const float*)d_in[25];
  const float* fcp = (const float*)d_in[26];
  const float* projW = (const float*)d_in[27];
  const float* projb = (const float*)d_in[28];
  float* dout = (float*)d_out;

  float* ws = (float*)d_ws;
  size_t off = 0;
  auto alloc = [&](size_t nel) { float* p = ws + off; off += nel; return p; };
  float* A1 = alloc(640000);
  float* A2 = alloc(640000);
  f16_t* A1h = (f16_t*)alloc(320000);
  f16_t* A1l = (f16_t*)alloc(320000);
  f16_t* A2h = (f16_t*)alloc(320000);
  f16_t* A2l = (f16_t*)alloc(320000);
  float* Zg = alloc((size_t)ROWS_ * 384);
  float* U = alloc((size_t)ROWS_ * 64);
  float* h0 = alloc((size_t)ROWS_ * 64);
  float* h1 = alloc((size_t)ROWS_ * 64);
  float* txe = alloc((size_t)768 * 1600);
  float* tye = alloc((size_t)768 * 1600);
  float* hidb = alloc(7680);
  float* attv = alloc(512);
  float* wge0 = alloc(204 * 128);
  float* wce0 = alloc(204 * 64);
  float* wge1 = alloc(384 * 128);
  float* wce1 = alloc(384 * 64);
  float* wgd0 = alloc(204 * 128);
  float* wcd0 = alloc(204 * 64);
  float* wgd1 = alloc(384 * 128);
  float* wcd1 = alloc(384 * 64);

  hipMemsetAsync(h0, 0, (size_t)ROWS_ * 64 * sizeof(float), stream);
  hipMemsetAsync(h1, 0, (size_t)ROWS_ * 64 * sizeof(float), stream);

  // precompute graph operators + fp16 splits
  transp_kernel<<<2500, 256, 0, stream>>>(G, A1);
  gemm_t2<<<dim3(13, 13), 256, 0, stream>>>(A1, A2);
  split_fp16<<<2500, 256, 0, stream>>>(A1, A1h, A1l, 640000);
  split_fp16<<<2500, 256, 0, stream>>>(A2, A2h, A2l, 640000);

  // preprocess weights
  wcat_kernel<<<(68 * 128 + 255) / 256, 256, 0, stream>>>(enc_Wg0, wge0, 68, 128);
  wcat_kernel<<<(68 * 64 + 255) / 256, 256, 0, stream>>>(enc_Wc0, wce0, 68, 64);
  wcat_kernel<<<(128 * 128 + 255) / 256, 256, 0, stream>>>(enc_Wg1, wge1, 128, 128);
  wcat_kernel<<<(128 * 64 + 255) / 256, 256, 0, stream>>>(enc_Wc1, wce1, 128, 64);
  wcat_kernel<<<(68 * 128 + 255) / 256, 256, 0, stream>>>(dec_Wg0, wgd0, 68, 128);
  wcat_kernel<<<(68 * 64 + 255) / 256, 256, 0, stream>>>(dec_Wc0, wcd0, 68, 64);
  wcat_kernel<<<(128 * 128 + 255) / 256, 256, 0, stream>>>(dec_Wg1, wgd1, 128, 128);
  wcat_kernel<<<(128 * 64 + 255) / 256, 256, 0, stream>>>(dec_Wc1, wcd1, 128, 64);

  // time covariate embeddings
  mlp_hid<<<30, 256, 0, stream>>>(t_x, mlp_W1, mlp_b1, hidb, 768);
  mlp_out<<<4800, 256, 0, stream>>>(hidb, mlp_W2, mlp_b2, txe, 768);
  mlp_hid<<<30, 256, 0, stream>>>(t_y, mlp_W1, mlp_b1, hidb, 768);
  mlp_out<<<4800, 256, 0, stream>>>(hidb, mlp_W2, mlp_b2, tye, 768);

  auto run_cell = [&](int layer, const float* Wg, const float* bg, const float* Wc, const float* bc, float* h) {
    int Pin = layer ? 64 : 4;
    int P = layer ? 128 : 68;
    int ldz = 3 * P;
    int K3 = 3 * P;
    graph_mfma<<<dim3((P + 63) / 64, 7, 128), 256, 0, stream>>>(Zg, ldz, 0, P, P, A1h, A1l, A2h, A2l);
    proj_gemm<8, 0><<<dim3(1, 800), 256, 0, stream>>>(Zg, ldz, K3, Pin, Wg, bg, U, h, Zg);
    graph_mfma<<<dim3(1, 7, 128), 256, 0, stream>>>(Zg, ldz, Pin, 64, P, A1h, A1l, A2h, A2l);
    proj_gemm<4, 1><<<dim3(1, 800), 256, 0, stream>>>(Zg, ldz, K3, Pin, Wc, bc, U, h, Zg);
  };

  // encoder
  for (int t = 0; t < T_; ++t) {
    pack_enc0<<<13600, 256, 0, stream>>>(Zg, x_seq, txe, h0, t);
    run_cell(0, wge0, enc_bg0, wce0, enc_bc0, h0);
    pack_l1<<<25600, 256, 0, stream>>>(Zg, h0, h1);
    run_cell(1, wge1, enc_bg1, wce1, enc_bc1, h1);
  }

  // decoder
  for (int t = 0; t < HOR_; ++t) {
    pack_dec0<<<13600, 256, 0, stream>>>(Zg, dout, tye, h0, t);
    run_cell(0, wgd0, dec_bg0, wcd0, dec_bc0, h0);
    pack_l1<<<25600, 256, 0, stream>>>(Zg, h0, h1);
    run_cell(1, wgd1, dec_bg1, wcd1, dec_bc1, h1);
    memq_kernel<<<64, 256, 0, stream>>>(h1, Wa, memoryp, attv);
    outproj_kernel<<<200, 256, 0, stream>>>(h1, attv, fcp, projW, projb, dout, t);
  }
}

// Round 3
// 18428.325 us; speedup vs baseline: 2.1522x; 1.0383x over previous
//
#include <hip/hip_runtime.h>
#include <math.h>

#define B_ 64
#define T_ 12
#define N_ 800
#define CIN_ 2
#define H_ 64
#define HOR_ 12
#define TCI_ 60
#define TCH_ 2
#define KAPPA_ 0.05f
#define IN0_ 4
#define ROWS_ 51200  // B_*N_

typedef _Float16 f16_t;
typedef _Float16 half8 __attribute__((ext_vector_type(8)));
typedef float f32x4 __attribute__((ext_vector_type(4)));

__device__ __forceinline__ float sigm(float x) { return 1.0f / (1.0f + expf(-x)); }

// ---------------- precompute kernels ----------------

__global__ void transp_kernel(const float* __restrict__ G, float* __restrict__ A1) {
  int idx = blockIdx.x * 256 + threadIdx.x;
  if (idx >= N_ * N_) return;
  int m = idx / N_, n = idx - m * N_;
  A1[idx] = G[n * N_ + m];
}

// C = 2*A@A - I   (800x800, A row-major)
__global__ __launch_bounds__(256) void gemm_t2(const float* __restrict__ A, float* __restrict__ C) {
  int tid = threadIdx.x;
  int tx = tid & 15, ty = tid >> 4;
  int rowBase = blockIdx.y * 64, colBase = blockIdx.x * 64;
  __shared__ float As[16][68];
  __shared__ float Bs[16][68];
  float acc[4][4] = {};
  for (int k0 = 0; k0 < N_; k0 += 16) {
    __syncthreads();
#pragma unroll
    for (int e = tid; e < 1024; e += 256) {
      int r = e >> 4, c = e & 15;
      int gr = rowBase + r;
      As[c][r] = (gr < N_) ? A[gr * N_ + k0 + c] : 0.f;
    }
#pragma unroll
    for (int e = tid; e < 1024; e += 256) {
      int r = e >> 6, c = e & 63;
      int gc = colBase + c;
      Bs[r][c] = (gc < N_) ? A[(k0 + r) * N_ + gc] : 0.f;
    }
    __syncthreads();
#pragma unroll
    for (int kk = 0; kk < 16; ++kk) {
      float4 a4 = *(const float4*)&As[kk][ty * 4];
      float4 b4 = *(const float4*)&Bs[kk][tx * 4];
      float av[4] = {a4.x, a4.y, a4.z, a4.w};
      float bv[4] = {b4.x, b4.y, b4.z, b4.w};
#pragma unroll
      for (int i = 0; i < 4; ++i)
#pragma unroll
        for (int j = 0; j < 4; ++j) acc[i][j] += av[i] * bv[j];
    }
  }
#pragma unroll
  for (int i = 0; i < 4; ++i) {
    int m = rowBase + ty * 4 + i;
    if (m >= N_) continue;
#pragma unroll
    for (int j = 0; j < 4; ++j) {
      int n = colBase + tx * 4 + j;
      if (n < N_) C[m * N_ + n] = 2.f * acc[i][j] - (m == n ? 1.f : 0.f);
    }
  }
}

__global__ void tohalf(const float* __restrict__ A, f16_t* __restrict__ Ah, int n) {
  int i = blockIdx.x * 256 + threadIdx.x;
  if (i >= n) return;
  Ah[i] = (f16_t)A[i];
}

// fold kappa + transpose + split fp16 hi/lo. W[(3P) x NC] -> Wth/Wtl [NC x Kp] (Kp padded, zero pad)
__global__ void wsplit(const float* __restrict__ W, f16_t* __restrict__ Wth, f16_t* __restrict__ Wtl,
                       int P, int NC, int Kp) {
  int idx = blockIdx.x * 256 + threadIdx.x;
  if (idx >= Kp * NC) return;
  int i = idx / NC, c = idx - i * NC;
  float v = 0.f;
  if (i < 3 * P) {
    int k = i / P, p = i - k * P;
    if (k == 0)
      v = W[(size_t)p * NC + c] + KAPPA_ * (W[(size_t)(P + p) * NC + c] + W[(size_t)(2 * P + p) * NC + c]);
    else
      v = (1.f - KAPPA_) * W[(size_t)i * NC + c];
  }
  f16_t h = (f16_t)v;
  Wth[(size_t)c * Kp + i] = h;
  Wtl[(size_t)c * Kp + i] = (f16_t)((v - (float)h) * 2048.0f);
}

// ---------------- graph GEMM: pure fp16, both Chebyshev mats fused ----------------
// Zout_k[b][m][k*P+inOff+c] = sum_n A_k[m][n] * Z[b][n][inOff+c],  k=1,2
// Block: 128(M) x 64(N), 4 waves 2x2, wave 64x32, both mats. BK=32.
__global__ __launch_bounds__(256) void graph_mfma2(float* __restrict__ Z, int ldz, int inOff, int inW, int P,
                                                   const f16_t* __restrict__ A1h, const f16_t* __restrict__ A2h) {
  int tid = threadIdx.x;
  int b = blockIdx.z;
  float* Zb = Z + (size_t)b * N_ * ldz;
  const float* Zin = Zb + inOff;
  float* Zout1 = Zb + P + inOff;
  float* Zout2 = Zb + 2 * P + inOff;
  int rowBase = blockIdx.y * 128;
  int colBase = blockIdx.x * 64;

  __shared__ f16_t A1S[128 * 40];
  __shared__ f16_t A2S[128 * 40];
  __shared__ f16_t ZS[64 * 40];

  int lane = tid & 63, wid = tid >> 6;
  int waveM = wid >> 1, waveN = wid & 1;
  int lrow = lane & 15, lgrp = lane >> 4;

  int arow = tid >> 1, ahalf = tid & 1;  // A: 128 rows x 2 halves of 16 f16
  bool avalid = (rowBase + arow) < N_;
  int zc = tid & 63, zgrp = tid >> 6;    // Z: 64 cols x 4 groups of 8 k's
  bool zvalid = (colBase + zc) < inW;

  f32x4 acc1[4][2], acc2[4][2];
#pragma unroll
  for (int mt = 0; mt < 4; ++mt)
#pragma unroll
    for (int nt = 0; nt < 2; ++nt) {
      acc1[mt][nt] = (f32x4){0.f, 0.f, 0.f, 0.f};
      acc2[mt][nt] = (f32x4){0.f, 0.f, 0.f, 0.f};
    }

#pragma unroll 2
  for (int k0 = 0; k0 < N_; k0 += 32) {
    __syncthreads();
    {  // A stage (both mats, hi only)
      size_t gofs = (size_t)(rowBase + arow) * N_ + k0 + ahalf * 16;
      uint4 zz = {0u, 0u, 0u, 0u};
      uint4 a0 = avalid ? *(const uint4*)(A1h + gofs) : zz;
      uint4 a1 = avalid ? *(const uint4*)(A1h + gofs + 8) : zz;
      uint4 b0 = avalid ? *(const uint4*)(A2h + gofs) : zz;
      uint4 b1 = avalid ? *(const uint4*)(A2h + gofs + 8) : zz;
      int s = arow * 40 + ahalf * 16;
      *(uint4*)(A1S + s) = a0;
      *(uint4*)(A1S + s + 8) = a1;
      *(uint4*)(A2S + s) = b0;
      *(uint4*)(A2S + s + 8) = b1;
    }
    {  // Z stage: fp32 rows -> f16, transposed [c][k]
      const float* src = Zin + (size_t)(k0 + zgrp * 8) * ldz + colBase + zc;
      half8 vh;
#pragma unroll
      for (int i = 0; i < 8; ++i) {
        float zv = zvalid ? src[(size_t)i * ldz] : 0.f;
        vh[i] = (f16_t)zv;
      }
      *(half8*)(ZS + zc * 40 + zgrp * 8) = vh;
    }
    __syncthreads();
    half8 fz[2];
#pragma unroll
    for (int nt = 0; nt < 2; ++nt) {
      int c = waveN * 32 + nt * 16 + lrow;
      fz[nt] = *(const half8*)(ZS + c * 40 + lgrp * 8);
    }
#pragma unroll
    for (int mt = 0; mt < 4; ++mt) {
      int r = waveM * 64 + mt * 16 + lrow;
      half8 fa1 = *(const half8*)(A1S + r * 40 + lgrp * 8);
      half8 fa2 = *(const half8*)(A2S + r * 40 + lgrp * 8);
#pragma unroll
      for (int nt = 0; nt < 2; ++nt) {
        acc1[mt][nt] = __builtin_amdgcn_mfma_f32_16x16x32_f16(fa1, fz[nt], acc1[mt][nt], 0, 0, 0);
        acc2[mt][nt] = __builtin_amdgcn_mfma_f32_16x16x32_f16(fa2, fz[nt], acc2[mt][nt], 0, 0, 0);
      }
    }
  }

#pragma unroll
  for (int mt = 0; mt < 4; ++mt)
#pragma unroll
    for (int nt = 0; nt < 2; ++nt) {
      int c = colBase + waveN * 32 + nt * 16 + lrow;
      if (c < inW) {
#pragma unroll
        for (int j = 0; j < 4; ++j) {
          int r = rowBase + waveM * 64 + mt * 16 + lgrp * 4 + j;
          if (r < N_) {
            Zout1[(size_t)r * ldz + c] = acc1[mt][nt][j];
            Zout2[(size_t)r * ldz + c] = acc2[mt][nt][j];
          }
        }
      }
    }
}

// ---------------- projection GEMMs: MFMA fp16x3 with fused GRU epilogues ----------------
// GATE: (51200 x K3) @ (K3 x 128): block 128 rows x 128 cols, 4 waves 2x2, wave 64x64.
__global__ __launch_bounds__(256) void proj_gate(const float* __restrict__ Z, int ldz, int K3, int Kp, int Pin,
                                                 const f16_t* __restrict__ Wth, const f16_t* __restrict__ Wtl,
                                                 const float* __restrict__ bias,
                                                 float* __restrict__ U, const float* __restrict__ h,
                                                 float* __restrict__ Zw) {
  int tid = threadIdx.x;
  int lane = tid & 63, wid = tid >> 6;
  int waveM = wid >> 1, waveN = wid & 1;
  int lrow = lane & 15, lgrp = lane >> 4;
  int rowBase = blockIdx.y * 128;

  __shared__ f16_t ZhS[128 * 40];
  __shared__ f16_t ZlS[128 * 40];
  __shared__ f16_t WhS[128 * 40];
  __shared__ f16_t WlS[128 * 40];

  int zrow = tid >> 1, zhalf = tid & 1;  // Z: 128 rows x 2 halves of 16
  int wcol = tid >> 1, whalf = tid & 1;  // W: 128 cols x 2 halves of 16

  f32x4 aM[4][4], aC[4][4];
#pragma unroll
  for (int mt = 0; mt < 4; ++mt)
#pragma unroll
    for (int nt = 0; nt < 4; ++nt) {
      aM[mt][nt] = (f32x4){0.f, 0.f, 0.f, 0.f};
      aC[mt][nt] = (f32x4){0.f, 0.f, 0.f, 0.f};
    }

  for (int k0 = 0; k0 < Kp; k0 += 32) {
    __syncthreads();
    {  // Z stage: split fp32 -> hi/lo
      const float* src = Z + (size_t)(rowBase + zrow) * ldz + k0 + zhalf * 16;
      f16_t hb[16], lb[16];
      if (k0 + 32 <= K3) {
#pragma unroll
        for (int v4 = 0; v4 < 4; ++v4) {
          float4 v = *(const float4*)(src + v4 * 4);
          float vv[4] = {v.x, v.y, v.z, v.w};
#pragma unroll
          for (int j = 0; j < 4; ++j) {
            f16_t hh = (f16_t)vv[j];
            hb[v4 * 4 + j] = hh;
            lb[v4 * 4 + j] = (f16_t)((vv[j] - (float)hh) * 2048.0f);
          }
        }
      } else {
#pragma unroll
        for (int i = 0; i < 16; ++i) {
          int kk = k0 + zhalf * 16 + i;
          float a = (kk < K3) ? src[i] : 0.f;
          f16_t hh = (f16_t)a;
          hb[i] = hh;
          lb[i] = (f16_t)((a - (float)hh) * 2048.0f);
        }
      }
      int s = zrow * 40 + zhalf * 16;
      *(half8*)(ZhS + s) = *(half8*)hb;
      *(half8*)(ZhS + s + 8) = *(half8*)(hb + 8);
      *(half8*)(ZlS + s) = *(half8*)lb;
      *(half8*)(ZlS + s + 8) = *(half8*)(lb + 8);
    }
    {  // W stage (padded, no guards)
      size_t g = (size_t)wcol * Kp + k0 + whalf * 16;
      uint4 h0v = *(const uint4*)(Wth + g);
      uint4 h1v = *(const uint4*)(Wth + g + 8);
      uint4 l0v = *(const uint4*)(Wtl + g);
      uint4 l1v = *(const uint4*)(Wtl + g + 8);
      int s = wcol * 40 + whalf * 16;
      *(uint4*)(WhS + s) = h0v;
      *(uint4*)(WhS + s + 8) = h1v;
      *(uint4*)(WlS + s) = l0v;
      *(uint4*)(WlS + s + 8) = l1v;
    }
    __syncthreads();
    half8 fwh[4], fwl[4];
#pragma unroll
    for (int nt = 0; nt < 4; ++nt) {
      int c = waveN * 64 + nt * 16 + lrow;
      fwh[nt] = *(const half8*)(WhS + c * 40 + lgrp * 8);
      fwl[nt] = *(const half8*)(WlS + c * 40 + lgrp * 8);
    }
#pragma unroll
    for (int mt = 0; mt < 4; ++mt) {
      int r = waveM * 64 + mt * 16 + lrow;
      half8 fzh = *(const half8*)(ZhS + r * 40 + lgrp * 8);
      half8 fzl = *(const half8*)(ZlS + r * 40 + lgrp * 8);
#pragma unroll
      for (int nt = 0; nt < 4; ++nt) {
        aM[mt][nt] = __builtin_amdgcn_mfma_f32_16x16x32_f16(fzh, fwh[nt], aM[mt][nt], 0, 0, 0);
        aC[mt][nt] = __builtin_amdgcn_mfma_f32_16x16x32_f16(fzh, fwl[nt], aC[mt][nt], 0, 0, 0);
        aC[mt][nt] = __builtin_amdgcn_mfma_f32_16x16x32_f16(fzl, fwh[nt], aC[mt][nt], 0, 0, 0);
      }
    }
  }

#pragma unroll
  for (int mt = 0; mt < 4; ++mt)
#pragma unroll
    for (int nt = 0; nt < 4; ++nt) {
      int col = waveN * 64 + nt * 16 + lrow;
#pragma unroll
      for (int j = 0; j < 4; ++j) {
        int row = rowBase + waveM * 64 + mt * 16 + lgrp * 4 + j;
        float v = aM[mt][nt][j] + aC[mt][nt][j] * (1.0f / 2048.0f) + bias[col];
        if (col < H_) {
          U[(size_t)row * H_ + col] = sigm(v);
        } else {
          int jj = col - H_;
          Zw[(size_t)row * ldz + Pin + jj] = sigm(v) * h[(size_t)row * H_ + jj];
        }
      }
    }
}

// CAND: (51200 x K3) @ (K3 x 64): block 256 rows x 64 cols, 4 waves stacked M, wave 64x64.
__global__ __launch_bounds__(256) void proj_cand(const float* __restrict__ Z, int ldz, int K3, int Kp,
                                                 const f16_t* __restrict__ Wth, const f16_t* __restrict__ Wtl,
                                                 const float* __restrict__ bias,
                                                 const float* __restrict__ U, float* __restrict__ h) {
  int tid = threadIdx.x;
  int lane = tid & 63, wid = tid >> 6;
  int lrow = lane & 15, lgrp = lane >> 4;
  int rowBase = blockIdx.y * 256;

  __shared__ f16_t ZhS[256 * 40];
  __shared__ f16_t ZlS[256 * 40];
  __shared__ f16_t WhS[64 * 40];
  __shared__ f16_t WlS[64 * 40];

  int wcol = tid >> 2, wq = tid & 3;

  f32x4 aM[4][4], aC[4][4];
#pragma unroll
  for (int mt = 0; mt < 4; ++mt)
#pragma unroll
    for (int nt = 0; nt < 4; ++nt) {
      aM[mt][nt] = (f32x4){0.f, 0.f, 0.f, 0.f};
      aC[mt][nt] = (f32x4){0.f, 0.f, 0.f, 0.f};
    }

  for (int k0 = 0; k0 < Kp; k0 += 32) {
    __syncthreads();
    {  // Z stage: one row per thread, 32 k's
      const float* src = Z + (size_t)(rowBase + tid) * ldz + k0;
      f16_t hb[32], lb[32];
      if (k0 + 32 <= K3) {
#pragma unroll
        for (int v4 = 0; v4 < 8; ++v4) {
          float4 v = *(const float4*)(src + v4 * 4);
          float vv[4] = {v.x, v.y, v.z, v.w};
#pragma unroll
          for (int j = 0; j < 4; ++j) {
            f16_t hh = (f16_t)vv[j];
            hb[v4 * 4 + j] = hh;
            lb[v4 * 4 + j] = (f16_t)((vv[j] - (float)hh) * 2048.0f);
          }
        }
      } else {
#pragma unroll
        for (int i = 0; i < 32; ++i) {
          int kk = k0 + i;
          float a = (kk < K3) ? src[i] : 0.f;
          f16_t hh = (f16_t)a;
          hb[i] = hh;
          lb[i] = (f16_t)((a - (float)hh) * 2048.0f);
        }
      }
      int s = tid * 40;
#pragma unroll
      for (int g = 0; g < 4; ++g) {
        *(half8*)(ZhS + s + g * 8) = *(half8*)(hb + g * 8);
        *(half8*)(ZlS + s + g * 8) = *(half8*)(lb + g * 8);
      }
    }
    {  // W stage
      size_t g = (size_t)wcol * Kp + k0 + wq * 8;
      uint4 hv = *(const uint4*)(Wth + g);
      uint4 lv = *(const uint4*)(Wtl + g);
      int s = wcol * 40 + wq * 8;
      *(uint4*)(WhS + s) = hv;
      *(uint4*)(WlS + s) = lv;
    }
    __syncthreads();
    half8 fwh[4], fwl[4];
#pragma unroll
    for (int nt = 0; nt < 4; ++nt) {
      int c = nt * 16 + lrow;
      fwh[nt] = *(const half8*)(WhS + c * 40 + lgrp * 8);
      fwl[nt] = *(const half8*)(WlS + c * 40 + lgrp * 8);
    }
#pragma unroll
    for (int mt = 0; mt < 4; ++mt) {
      int r = wid * 64 + mt * 16 + lrow;
      half8 fzh = *(const half8*)(ZhS + r * 40 + lgrp * 8);
      half8 fzl = *(const half8*)(ZlS + r * 40 + lgrp * 8);
#pragma unroll
      for (int nt = 0; nt < 4; ++nt) {
        aM[mt][nt] = __builtin_amdgcn_mfma_f32_16x16x32_f16(fzh, fwh[nt], aM[mt][nt], 0, 0, 0);
        aC[mt][nt] = __builtin_amdgcn_mfma_f32_16x16x32_f16(fzh, fwl[nt], aC[mt][nt], 0, 0, 0);
        aC[mt][nt] = __builtin_amdgcn_mfma_f32_16x16x32_f16(fzl, fwh[nt], aC[mt][nt], 0, 0, 0);
      }
    }
  }

#pragma unroll
  for (int mt = 0; mt < 4; ++mt)
#pragma unroll
    for (int nt = 0; nt < 4; ++nt) {
      int col = nt * 16 + lrow;
#pragma unroll
      for (int j = 0; j < 4; ++j) {
        int row = rowBase + wid * 64 + mt * 16 + lgrp * 4 + j;
        float v = aM[mt][nt][j] + aC[mt][nt][j] * (1.0f / 2048.0f) + bias[col];
        float cc = tanhf(v);
        float u = U[(size_t)row * H_ + col];
        float hv = h[(size_t)row * H_ + col];
        h[(size_t)row * H_ + col] = (1.f - u) * hv + u * cc;
      }
    }
}

// ---------------- pack / misc kernels ----------------

__global__ void pack_enc0(float* __restrict__ Z, const float* __restrict__ xseq,
                          const float* __restrict__ emb, const float* __restrict__ h0, int t) {
  int idx = blockIdx.x * 256 + threadIdx.x;
  if (idx >= ROWS_ * 68) return;
  int row = idx / 68, c = idx - row * 68;
  int b = row / N_, n = row - b * N_;
  float v;
  if (c < CIN_) v = xseq[((size_t)(b * T_ + t) * N_ + n) * CIN_ + c];
  else if (c < IN0_) v = emb[(size_t)(b * T_ + t) * (N_ * TCH_) + n * TCH_ + (c - CIN_)];
  else v = h0[(size_t)row * H_ + (c - IN0_)];
  Z[(size_t)row * 204 + c] = v;
}

__global__ void pack_dec0(float* __restrict__ Z, const float* __restrict__ dout,
                          const float* __restrict__ emb, const float* __restrict__ h0, int t) {
  int idx = blockIdx.x * 256 + threadIdx.x;
  if (idx >= ROWS_ * 68) return;
  int row = idx / 68, c = idx - row * 68;
  int b = row / N_, n = row - b * N_;
  float v;
  if (c < CIN_) v = (t == 0) ? 0.f : dout[((size_t)(b * HOR_ + (t - 1)) * N_ + n) * CIN_ + c];
  else if (c < IN0_) v = emb[(size_t)(b * HOR_ + t) * (N_ * TCH_) + n * TCH_ + (c - CIN_)];
  else v = h0[(size_t)row * H_ + (c - IN0_)];
  Z[(size_t)row * 204 + c] = v;
}

__global__ void pack_l1(float* __restrict__ Z, const float* __restrict__ h0, const float* __restrict__ h1) {
  int idx = blockIdx.x * 256 + threadIdx.x;
  if (idx >= ROWS_ * 128) return;
  int row = idx >> 7, c = idx & 127;
  Z[(size_t)row * 384 + c] = (c < 64) ? h0[(size_t)row * 64 + c] : h1[(size_t)row * 64 + (c - 64)];
}

__global__ void mlp_hid(const float* __restrict__ tin, const float* __restrict__ W1,
                        const float* __restrict__ b1, float* __restrict__ hid, int Rtot) {
  int idx = blockIdx.x * 256 + threadIdx.x;
  if (idx >= Rtot * 10) return;
  int r = idx / 10, j = idx - r * 10;
  float a = b1[j];
  for (int k = 0; k < TCI_; ++k) a += tin[(size_t)r * TCI_ + k] * W1[k * 10 + j];
  hid[idx] = a;
}

__global__ void mlp_out(const float* __restrict__ hid, const float* __restrict__ W2,
                        const float* __restrict__ b2, float* __restrict__ emb, int Rtot) {
  int idx = blockIdx.x * 256 + threadIdx.x;
  if (idx >= Rtot * 1600) return;
  int r = idx / 1600, o = idx - r * 1600;
  float a = b2[o];
#pragma unroll
  for (int k = 0; k < 10; ++k) a += hid[r * 10 + k] * W2[k * 1600 + o];
  emb[idx] = a;
}

// memq stage1: partial[b][chunk][8] over 16 k-chunks of 3200
__global__ __launch_bounds__(256) void memq1(const float* __restrict__ h1, const float* __restrict__ Wa,
                                             float* __restrict__ partial) {
  int cx = blockIdx.x, b = blockIdx.y;
  int i0 = cx * 3200;
  __shared__ float red[256][8];
  float acc[8] = {};
  const float* hrow = h1 + (size_t)b * 51200;
  for (int i = i0 + threadIdx.x; i < i0 + 3200; i += 256) {
    float hv = hrow[i];
#pragma unroll
    for (int j = 0; j < 8; ++j) acc[j] += hv * Wa[(size_t)i * 8 + j];
  }
#pragma unroll
  for (int j = 0; j < 8; ++j) red[threadIdx.x][j] = acc[j];
  __syncthreads();
  for (int s = 128; s > 0; s >>= 1) {
    if (threadIdx.x < s) {
#pragma unroll
      for (int j = 0; j < 8; ++j) red[threadIdx.x][j] += red[threadIdx.x + s][j];
    }
    __syncthreads();
  }
  if (threadIdx.x == 0) {
#pragma unroll
    for (int j = 0; j < 8; ++j) partial[((size_t)b * 16 + cx) * 8 + j] = red[0][j];
  }
}

// memq stage2: reduce + softmax + attvec  (64 threads, thread = batch)
__global__ void memq2(const float* __restrict__ partial, const float* __restrict__ mem,
                      float* __restrict__ attvec) {
  int b = threadIdx.x;
  if (b >= 64) return;
  float q[8] = {};
  for (int cx = 0; cx < 16; ++cx)
#pragma unroll
    for (int j = 0; j < 8; ++j) q[j] += partial[((size_t)b * 16 + cx) * 8 + j];
  float sco[4], mx = -1e30f;
#pragma unroll
  for (int m = 0; m < 4; ++m) {
    float s = 0.f;
#pragma unroll
    for (int d = 0; d < 8; ++d) s += q[d] * mem[m * 8 + d];
    sco[m] = s;
    mx = fmaxf(mx, s);
  }
  float se = 0.f;
#pragma unroll
  for (int m = 0; m < 4; ++m) { sco[m] = expf(sco[m] - mx); se += sco[m]; }
#pragma unroll
  for (int d = 0; d < 8; ++d) {
    float av = 0.f;
#pragma unroll
    for (int m = 0; m < 4; ++m) av += (sco[m] / se) * mem[m * 8 + d];
    attvec[b * 8 + d] = av;
  }
}

__global__ void outproj_kernel(const float* __restrict__ h1, const float* __restrict__ attvec,
                               const float* __restrict__ fc, const float* __restrict__ projW,
                               const float* __restrict__ projb, float* __restrict__ dout, int t) {
  int row = blockIdx.x * 256 + threadIdx.x;
  if (row >= ROWS_) return;
  int b = row / N_, n = row - b * N_;
  const float* av = attvec + b * 8;
  float attm[8];
#pragma unroll
  for (int d = 0; d < 8; ++d) {
    float s = 0.f;
#pragma unroll
    for (int m = 0; m < 8; ++m) s += av[m] * fc[(size_t)m * 6400 + n * 8 + d];
    attm[d] = s;
  }
  float o0 = projb[0], o1 = projb[1];
  for (int j = 0; j < 64; ++j) {
    float hv = h1[(size_t)row * 64 + j];
    o0 += hv * projW[j * 2 + 0];
    o1 += hv * projW[j * 2 + 1];
  }
#pragma unroll
  for (int d = 0; d < 8; ++d) {
    o0 += attm[d] * projW[(64 + d) * 2 + 0];
    o1 += attm[d] * projW[(64 + d) * 2 + 1];
  }
  o0 = fmaxf(o0, 0.f);
  o1 = fmaxf(o1, 0.f);
  size_t base = ((size_t)(b * HOR_ + t) * N_ + n) * 2;
  dout[base + 0] = o0;
  dout[base + 1] = o1;
}

// ---------------- host ----------------

extern "C" void kernel_launch(void* const* d_in, const int* in_sizes, int n_in,
                              void* d_out, int out_size, void* d_ws, size_t ws_size,
                              hipStream_t stream) {
  const float* x_seq = (const float*)d_in[0];
  const float* t_x = (const float*)d_in[1];
  const float* t_y = (const float*)d_in[2];
  const float* G = (const float*)d_in[3];
  const float* enc_Wg0 = (const float*)d_in[4];
  const float* enc_bg0 = (const float*)d_in[5];
  const float* enc_Wc0 = (const float*)d_in[6];
  const float* enc_bc0 = (const float*)d_in[7];
  const float* enc_Wg1 = (const float*)d_in[8];
  const float* enc_bg1 = (const float*)d_in[9];
  const float* enc_Wc1 = (const float*)d_in[10];
  const float* enc_bc1 = (const float*)d_in[11];
  const float* dec_Wg0 = (const float*)d_in[12];
  const float* dec_bg0 = (const float*)d_in[13];
  const float* dec_Wc0 = (const float*)d_in[14];
  const float* dec_bc0 = (const float*)d_in[15];
  const float* dec_Wg1 = (const float*)d_in[16];
  const float* dec_bg1 = (const float*)d_in[17];
  const float* dec_Wc1 = (const float*)d_in[18];
  const float* dec_bc1 = (const float*)d_in[19];
  const float* mlp_W1 = (const float*)d_in[20];
  const float* mlp_b1 = (const float*)d_in[21];
  const float* mlp_W2 = (const float*)d_in[22];
  const float* mlp_b2 = (const float*)d_in[23];
  const float* memoryp = (const float*)d_in[24];
  const float* Wa = (const float*)d_in[25];
  const float* fcp = (const float*)d_in[26];
  const float* projW = (const float*)d_in[27];
  const float* projb = (const float*)d_in[28];
  float* dout = (float*)d_out;

  float* ws = (float*)d_ws;
  size_t off = 0;
  auto alloc = [&](size_t nel) { float* p = ws + off; off += nel; return p; };
  float* A1 = alloc(640000);
  float* A2 = alloc(640000);
  f16_t* A1h = (f16_t*)alloc(320000);
  f16_t* A2h = (f16_t*)alloc(320000);
  float* Zg = alloc((size_t)ROWS_ * 384);
  float* U = alloc((size_t)ROWS_ * 64);
  float* h0 = alloc((size_t)ROWS_ * 64);
  float* h1 = alloc((size_t)ROWS_ * 64);
  float* txe = alloc((size_t)768 * 1600);
  float* tye = alloc((size_t)768 * 1600);
  float* hidb = alloc(7680);
  float* attv = alloc(512);
  float* partial = alloc(64 * 16 * 8);
  // weight fp16 planes (alloc counts in floats = f16/2)
  f16_t* wge0h = (f16_t*)alloc(224 * 128 / 2); f16_t* wge0l = (f16_t*)alloc(224 * 128 / 2);
  f16_t* wce0h = (f16_t*)alloc(224 * 64 / 2);  f16_t* wce0l = (f16_t*)alloc(224 * 64 / 2);
  f16_t* wge1h = (f16_t*)alloc(384 * 128 / 2); f16_t* wge1l = (f16_t*)alloc(384 * 128 / 2);
  f16_t* wce1h = (f16_t*)alloc(384 * 64 / 2);  f16_t* wce1l = (f16_t*)alloc(384 * 64 / 2);
  f16_t* wgd0h = (f16_t*)alloc(224 * 128 / 2); f16_t* wgd0l = (f16_t*)alloc(224 * 128 / 2);
  f16_t* wcd0h = (f16_t*)alloc(224 * 64 / 2);  f16_t* wcd0l = (f16_t*)alloc(224 * 64 / 2);
  f16_t* wgd1h = (f16_t*)alloc(384 * 128 / 2); f16_t* wgd1l = (f16_t*)alloc(384 * 128 / 2);
  f16_t* wcd1h = (f16_t*)alloc(384 * 64 / 2);  f16_t* wcd1l = (f16_t*)alloc(384 * 64 / 2);

  hipMemsetAsync(h0, 0, (size_t)ROWS_ * 64 * sizeof(float), stream);
  hipMemsetAsync(h1, 0, (size_t)ROWS_ * 64 * sizeof(float), stream);

  // graph operators
  transp_kernel<<<2500, 256, 0, stream>>>(G, A1);
  gemm_t2<<<dim3(13, 13), 256, 0, stream>>>(A1, A2);
  tohalf<<<2500, 256, 0, stream>>>(A1, A1h, 640000);
  tohalf<<<2500, 256, 0, stream>>>(A2, A2h, 640000);

  // weights: fold kappa, transpose, split
  wsplit<<<(224 * 128 + 255) / 256, 256, 0, stream>>>(enc_Wg0, wge0h, wge0l, 68, 128, 224);
  wsplit<<<(224 * 64 + 255) / 256, 256, 0, stream>>>(enc_Wc0, wce0h, wce0l, 68, 64, 224);
  wsplit<<<(384 * 128 + 255) / 256, 256, 0, stream>>>(enc_Wg1, wge1h, wge1l, 128, 128, 384);
  wsplit<<<(384 * 64 + 255) / 256, 256, 0, stream>>>(enc_Wc1, wce1h, wce1l, 128, 64, 384);
  wsplit<<<(224 * 128 + 255) / 256, 256, 0, stream>>>(dec_Wg0, wgd0h, wgd0l, 68, 128, 224);
  wsplit<<<(224 * 64 + 255) / 256, 256, 0, stream>>>(dec_Wc0, wcd0h, wcd0l, 68, 64, 224);
  wsplit<<<(384 * 128 + 255) / 256, 256, 0, stream>>>(dec_Wg1, wgd1h, wgd1l, 128, 128, 384);
  wsplit<<<(384 * 64 + 255) / 256, 256, 0, stream>>>(dec_Wc1, wcd1h, wcd1l, 128, 64, 384);

  // time covariate embeddings
  mlp_hid<<<30, 256, 0, stream>>>(t_x, mlp_W1, mlp_b1, hidb, 768);
  mlp_out<<<4800, 256, 0, stream>>>(hidb, mlp_W2, mlp_b2, txe, 768);
  mlp_hid<<<30, 256, 0, stream>>>(t_y, mlp_W1, mlp_b1, hidb, 768);
  mlp_out<<<4800, 256, 0, stream>>>(hidb, mlp_W2, mlp_b2, tye, 768);

  auto run_cell = [&](int layer, const f16_t* Wgh, const f16_t* Wgl, const float* bg,
                      const f16_t* Wch, const f16_t* Wcl, const float* bc, float* h) {
    int Pin = layer ? 64 : 4;
    int P = layer ? 128 : 68;
    int ldz = 3 * P;
    int K3 = 3 * P;
    int Kp = layer ? 384 : 224;
    graph_mfma2<<<dim3((P + 63) / 64, 7, 64), 256, 0, stream>>>(Zg, ldz, 0, P, P, A1h, A2h);
    proj_gate<<<dim3(1, 400), 256, 0, stream>>>(Zg, ldz, K3, Kp, Pin, Wgh, Wgl, bg, U, h, Zg);
    graph_mfma2<<<dim3(1, 7, 64), 256, 0, stream>>>(Zg, ldz, Pin, 64, P, A1h, A2h);
    proj_cand<<<dim3(1, 200), 256, 0, stream>>>(Zg, ldz, K3, Kp, Wch, Wcl, bc, U, h);
  };

  // encoder
  for (int t = 0; t < T_; ++t) {
    pack_enc0<<<13600, 256, 0, stream>>>(Zg, x_seq, txe, h0, t);
    run_cell(0, wge0h, wge0l, enc_bg0, wce0h, wce0l, enc_bc0, h0);
    pack_l1<<<25600, 256, 0, stream>>>(Zg, h0, h1);
    run_cell(1, wge1h, wge1l, enc_bg1, wce1h, wce1l, enc_bc1, h1);
  }

  // decoder
  for (int t = 0; t < HOR_; ++t) {
    pack_dec0<<<13600, 256, 0, stream>>>(Zg, dout, tye, h0, t);
    run_cell(0, wgd0h, wgd0l, dec_bg0, wcd0h, wcd0l, dec_bc0, h0);
    pack_l1<<<25600, 256, 0, stream>>>(Zg, h0, h1);
    run_cell(1, wgd1h, wgd1l, dec_bg1, wcd1h, wcd1l, dec_bc1, h1);
    memq1<<<dim3(16, 64), 256, 0, stream>>>(h1, Wa, partial);
    memq2<<<1, 64, 0, stream>>>(partial, memoryp, attv);
    outproj_kernel<<<200, 256, 0, stream>>>(h1, attv, fcp, projW, projb, dout, t);
  }
}